// Round 3
// baseline (427.112 us; speedup 1.0000x reference)
//
#include <hip/hip_runtime.h>
#include <stdint.h>

#define S 2048
#define HID 4096
#define NKV 8
#define HD 128
#define KV 1024
#define BATCH 2
#define NQKV 3072   // KV*3 (q_eff | k | v)
#define MROWS 4096  // B*S

typedef __attribute__((ext_vector_type(4))) float f32x4;
typedef __attribute__((ext_vector_type(8))) __bf16 bf16x8;
typedef __attribute__((ext_vector_type(8))) unsigned short ushort8;
typedef __attribute__((ext_vector_type(4))) unsigned short ushort4_t;
typedef __attribute__((ext_vector_type(4))) float float4_t;

// fp32 -> bf16 bits, round-to-nearest-even
__device__ __forceinline__ unsigned short f2bf(float f) {
    unsigned int u = __builtin_bit_cast(unsigned int, f);
    u += 0x7fffu + ((u >> 16) & 1u);
    return (unsigned short)(u >> 16);
}
__device__ __forceinline__ float bf2f(unsigned short s) {
    unsigned int u = ((unsigned int)s) << 16;
    return __builtin_bit_cast(float, u);
}

// async global->LDS, 16B per lane. LDS dest must be wave-uniform base + lane*16.
__device__ __forceinline__ void gl2lds16(const void* g, void* l) {
    __builtin_amdgcn_global_load_lds(
        (const __attribute__((address_space(1))) void*)(uintptr_t)(g),
        (__attribute__((address_space(3))) void*)(uintptr_t)(l),
        16, 0, 0);
}

// ---------------------------------------------------------------- cast x->bf16
__global__ __launch_bounds__(256) void castx_kernel(const float* __restrict__ x,
                                                    unsigned short* __restrict__ xb) {
    int i = (blockIdx.x * 256 + threadIdx.x) * 4;
    float4_t v = *(const float4_t*)&x[i];
    ushort4_t o;
    o.x = f2bf(v.x); o.y = f2bf(v.y); o.z = f2bf(v.z); o.w = f2bf(v.w);
    *(ushort4_t*)&xb[i] = o;
}

// ------------------------------------------- build WcatT[3072][4096] bf16
__global__ __launch_bounds__(256) void wcat_kernel(const float* __restrict__ wq,
                                                   const float* __restrict__ wk,
                                                   const float* __restrict__ wv,
                                                   unsigned short* __restrict__ WcatT) {
    __shared__ float T[64 * 65];
    const int tid = threadIdx.x;
    const int k0 = blockIdx.x * 64;
    const int n0 = blockIdx.y * 64;
    const float scale = 0.088388347648318447f;  // 1/sqrt(128)
#pragma unroll
    for (int i = 0; i < 16; i++) {
        int kl = (tid >> 6) + i * 4;
        int nl = tid & 63;
        int k = k0 + kl, n = n0 + nl;
        float v;
        if (n < KV) {
            int kvh = n >> 7, d = n & 127;
            const float* p = wq + (size_t)k * HID + kvh * 512 + d;
            v = (p[0] + p[128] + p[256] + p[384]) * scale;
        } else if (n < 2048) {
            v = wk[(size_t)k * KV + (n - KV)];
        } else {
            v = wv[(size_t)k * KV + (n - 2048)];
        }
        T[kl * 65 + nl] = v;
    }
    __syncthreads();
#pragma unroll
    for (int i = 0; i < 16; i++) {
        int nl = (tid >> 6) + i * 4;
        int kl = tid & 63;
        WcatT[(size_t)(n0 + nl) * HID + k0 + kl] = f2bf(T[kl * 65 + nl]);
    }
}

// ------------------------------------------- build woT[4096][1024] bf16 (wo^T)
__global__ __launch_bounds__(256) void wot_kernel(const float* __restrict__ wo,
                                                  unsigned short* __restrict__ woT) {
    __shared__ float T[64 * 65];
    const int tid = threadIdx.x;
    const int k0 = blockIdx.x * 64;
    const int n0 = blockIdx.y * 64;
#pragma unroll
    for (int i = 0; i < 16; i++) {
        int kl = (tid >> 6) + i * 4, nl = tid & 63;
        T[kl * 65 + nl] = wo[(size_t)(k0 + kl) * HID + n0 + nl];
    }
    __syncthreads();
#pragma unroll
    for (int i = 0; i < 16; i++) {
        int nl = (tid >> 6) + i * 4, kl = tid & 63;
        woT[(size_t)(n0 + nl) * KV + k0 + kl] = f2bf(T[kl * 65 + nl]);
    }
}

// ============================================================================
// 256x256 8-phase GEMM: C[M][N] = A[M][K] * Bt[N][K]^T, bf16 in.
// 512 thr / 8 waves (2M x 4N); per-wave C = 128x64. BK=64, 2 K-tiles per iter.
// LDS: 2 dbuf x 2 row-halves x [128][64] for A and B = 128 KiB -> 1 block/CU.
// st_16x32 swizzle via inverse-permuted global SOURCE + XORed ds_read address.
//
// BARRIER DISCIPLINE (the R2->R3 fix): bare s_barrier (NO memory-clobber asm).
// Memory-clobber asm around barriers made SIInsertWaitcnts drain lgkmcnt
// BEFORE the barrier -> all waves' ds_reads fully served before ANY wave
// MFMAs -> phase = LDS(576cyc) + MFMA(592cyc) serialized = measured 122.9us.
// With bare barriers the per-wave lgkm waits sit AFTER the barrier (compiler
// emits fine-grained lgkmcnt(N) at first MFMA use), so the LDS pipe serves
// waves in order while early waves MFMA -> LDS time hides under MFMA time.
// sched_barrier(0) pins each phase's reads/stages above its leading barrier,
// and pins next-phase reads below the vmcnt waits (the RAW hazard boundary).
// Cross-wave WAR stays sound: each wave's reads drain before its own MFMA
// (operand waits), which precedes the trailing barrier, which precedes any
// restage of that region.
// ============================================================================
#define SBAR() __builtin_amdgcn_s_barrier()
#define SCHED0() __builtin_amdgcn_sched_barrier(0)
#define WAITV6() asm volatile("s_waitcnt vmcnt(6)")

template <int OUT_BF16>
__global__ __launch_bounds__(512, 2) void gemm_bt8(const unsigned short* __restrict__ A,
                                                   const unsigned short* __restrict__ Bt,
                                                   void* __restrict__ Cv,
                                                   int M, int N, int K) {
    __shared__ unsigned short As[2][2][8192];
    __shared__ unsigned short Bs[2][2][8192];
    const int tid = threadIdx.x;
    const int lane = tid & 63, wave = tid >> 6;
    const int lm = lane & 15, quad = lane >> 4;
    const int wm = wave >> 2;            // M-half of the block this wave owns
    const int wn = wave & 3;             // N quarter
    const int wnh = wn >> 1;             // B row-half
    const int wnb = (wn & 1) * 4;        // B subtile row-group base within half

    // ---- XCD-aware bijective block swizzle (nwg % 8 == 0 for both call sites)
    const int nbx = gridDim.x;
    const int id = blockIdx.y * nbx + blockIdx.x;
    const int cpx = (nbx * gridDim.y) >> 3;
    const int sid = (id & 7) * cpx + (id >> 3);
    const int m0 = (sid / nbx) * 256;
    const int n0 = (sid % nbx) * 256;

    // ---- staging source offsets (inverse-st_16x32-swizzled global chunks)
    // chunk p (16B): LDS byte = p*16 (linear). psrc = p ^ (((p>>5)&1)<<1)
    size_t so0, so1;
    {
#pragma unroll
        for (int i = 0; i < 2; i++) {
            int p = i * 512 + tid;
            int ps = p ^ (((p >> 5) & 1) << 1);
            int s = ps >> 6, w = ps & 63;
            int row = ((s >> 1) << 4) + (w >> 2);
            int kc = ((s & 1) << 5) + ((w & 3) << 3);
            size_t off = (size_t)row * K + kc;
            if (i == 0) so0 = off; else so1 = off;
        }
    }
    const unsigned short* Agb = A + (size_t)m0 * K;
    const unsigned short* Bgb = Bt + (size_t)n0 * K;
    const size_t hK = (size_t)128 * K;

// stage one 64-row quarter (8KB) of a [128][64] LDS half; G = half base ptr
#define STLO(G, L) gl2lds16((G) + so0, (L) + (size_t)tid * 8)
#define STHI(G, L) gl2lds16((G) + so1, (L) + (size_t)(512 + tid) * 8)

    // ---- ds_read address: subtile s = rg*2+kk; within: lm*32 + swizzled col
    const int roff = lm * 32 + ((quad << 3) ^ (((lm >> 3) & 1) << 4));

#define LDA(mi, kk, BUF) a[(mi) & 3][kk] = *(const bf16x8*)&As[BUF][wm][(((mi) * 2 + (kk)) << 9) + roff]
#define LDB(ni, kk, BUF) b[ni][kk] = *(const bf16x8*)&Bs[BUF][wnh][(((wnb + (ni)) * 2 + (kk)) << 9) + roff]
#define RD_A_LO(BUF) { LDA(0,0,BUF); LDA(0,1,BUF); LDA(1,0,BUF); LDA(1,1,BUF); LDA(2,0,BUF); LDA(2,1,BUF); LDA(3,0,BUF); LDA(3,1,BUF); }
#define RD_A_HI(BUF) { LDA(4,0,BUF); LDA(4,1,BUF); LDA(5,0,BUF); LDA(5,1,BUF); LDA(6,0,BUF); LDA(6,1,BUF); LDA(7,0,BUF); LDA(7,1,BUF); }
#define RD_B_LO(BUF) { LDB(0,0,BUF); LDB(0,1,BUF); LDB(1,0,BUF); LDB(1,1,BUF); }
#define RD_B_HI(BUF) { LDB(2,0,BUF); LDB(2,1,BUF); LDB(3,0,BUF); LDB(3,1,BUF); }
#define MFMA_Q(MB, NB) do { \
    __builtin_amdgcn_s_setprio(1); \
    _Pragma("unroll") for (int i_ = 0; i_ < 4; i_++) \
    _Pragma("unroll") for (int j_ = 0; j_ < 2; j_++) \
    _Pragma("unroll") for (int k_ = 0; k_ < 2; k_++) \
        acc[(MB) + i_][(NB) + j_] = __builtin_amdgcn_mfma_f32_16x16x32_bf16( \
            a[i_][k_], b[(NB) + j_][k_], acc[(MB) + i_][(NB) + j_], 0, 0, 0); \
    __builtin_amdgcn_s_setprio(0); \
} while (0)

    f32x4 acc[8][4] = {};
    bf16x8 a[4][2], b[4][2];

    const int KT = K >> 6;   // 64-wide K-tiles
    const int NT = KT >> 1;  // iterations (2 tiles each)

    // ---- prologue: tile0 -> buf0 (8 quarters), tile1 -> buf1 (A-lo,B-lo,B-hi)
    STLO(Agb, &As[0][0][0]); STLO(Agb + hK, &As[0][1][0]);
    STHI(Agb, &As[0][0][0]); STHI(Agb + hK, &As[0][1][0]);
    STLO(Bgb, &Bs[0][0][0]); STLO(Bgb + hK, &Bs[0][1][0]);
    STHI(Bgb, &Bs[0][0][0]); STHI(Bgb + hK, &Bs[0][1][0]);
    STLO(Agb + 64, &As[1][0][0]); STLO(Agb + hK + 64, &As[1][1][0]);
    STLO(Bgb + 64, &Bs[1][0][0]); STLO(Bgb + hK + 64, &Bs[1][1][0]);
    STHI(Bgb + 64, &Bs[1][0][0]); STHI(Bgb + hK + 64, &Bs[1][1][0]);
    WAITV6();  // 14 outstanding -> retire 8 = tile0 complete; tile1's 6 in flight
    SCHED0();  // no loop ds_read may hoist above the wait
    SBAR();

    for (int t = 0; t < NT; ++t) {
        const size_t k1 = (size_t)(2 * t + 1) * 64;
        int t2i = 2 * t + 2; if (t2i >= KT) t2i = KT - 1;  // tail: harmless restage
        int t3i = 2 * t + 3; if (t3i >= KT) t3i = KT - 1;
        const size_t k2 = (size_t)t2i * 64, k3 = (size_t)t3i * 64;

        // P1: buf0 A-lo+B-lo reads; stage buf1.A-hi <- t1
        RD_A_LO(0); RD_B_LO(0);
        STHI(Agb + k1, &As[1][0][0]); STHI(Agb + hK + k1, &As[1][1][0]);
        SCHED0(); SBAR(); MFMA_Q(0, 0); SBAR();

        // P2: buf0 B-hi; stage buf0.A-lo <- t2 (old A-lo read at P1)
        RD_B_HI(0);
        STLO(Agb + k2, &As[0][0][0]); STLO(Agb + hK + k2, &As[0][1][0]);
        SCHED0(); SBAR(); MFMA_Q(0, 2); SBAR();

        // P3: buf0 A-hi; stage buf0.B-lo <- t2 (old B-lo read at P1)
        RD_A_HI(0);
        STLO(Bgb + k2, &Bs[0][0][0]); STLO(Bgb + hK + k2, &Bs[0][1][0]);
        SCHED0(); SBAR(); MFMA_Q(4, 2); SBAR();

        // P4: stage buf0.B-hi <- t2 (old read at P2); wait -> buf1 complete
        STHI(Bgb + k2, &Bs[0][0][0]); STHI(Bgb + hK + k2, &Bs[0][1][0]);
        SCHED0(); SBAR(); MFMA_Q(4, 0);
        WAITV6();  // retire through P1's stage: all of buf1/t1 resident
        SCHED0();  // P5's buf1 reads must not hoist above this wait
        SBAR();

        // P5: buf1 A-lo+B-lo reads; stage buf0.A-hi <- t2 (old read at P3)
        RD_A_LO(1); RD_B_LO(1);
        STHI(Agb + k2, &As[0][0][0]); STHI(Agb + hK + k2, &As[0][1][0]);
        SCHED0(); SBAR(); MFMA_Q(0, 0); SBAR();

        // P6: buf1 B-hi; stage buf1.A-lo <- t3 (old read at P5)
        RD_B_HI(1);
        STLO(Agb + k3, &As[1][0][0]); STLO(Agb + hK + k3, &As[1][1][0]);
        SCHED0(); SBAR(); MFMA_Q(0, 2); SBAR();

        // P7: buf1 A-hi; stage buf1.B-lo <- t3 (old read at P5)
        RD_A_HI(1);
        STLO(Bgb + k3, &Bs[1][0][0]); STLO(Bgb + hK + k3, &Bs[1][1][0]);
        SCHED0(); SBAR(); MFMA_Q(4, 2); SBAR();

        // P8: stage buf1.B-hi <- t3 (old read at P6); wait -> buf0 complete
        STHI(Bgb + k3, &Bs[1][0][0]); STHI(Bgb + hK + k3, &Bs[1][1][0]);
        SCHED0(); SBAR(); MFMA_Q(4, 0);
        WAITV6();  // retire through P5's stage: all of buf0/t2 resident
        SCHED0();  // next P1's buf0 reads must not hoist above this wait
        SBAR();
    }

    // ---- epilogue: C write (D layout: row = quad*4+r, col = lm)
    const int crow0 = m0 + wm * 128 + quad * 4;
    const int ccol0 = n0 + wn * 64 + lm;
#pragma unroll
    for (int mi = 0; mi < 8; mi++)
#pragma unroll
        for (int ni = 0; ni < 4; ni++)
#pragma unroll
            for (int r = 0; r < 4; r++) {
                const int row = crow0 + mi * 16 + r;
                const int col = ccol0 + ni * 16;
                if (OUT_BF16)
                    ((unsigned short*)Cv)[(size_t)row * N + col] = f2bf(acc[mi][ni][r]);
                else
                    ((float*)Cv)[(size_t)row * N + col] = acc[mi][ni][r];
            }
#undef LDA
#undef LDB
#undef RD_A_LO
#undef RD_A_HI
#undef RD_B_LO
#undef RD_B_HI
#undef MFMA_Q
#undef STLO
#undef STHI
}

// ------------------------------------------- Vt[(b*8+h)*128 + d][s] from QKV v-part
__global__ __launch_bounds__(256) void vt_kernel(const unsigned short* __restrict__ QKV,
                                                 unsigned short* __restrict__ Vt) {
    __shared__ unsigned short T[128 * 136];
    const int tid = threadIdx.x;
    const int st = blockIdx.x;
    const int bh = blockIdx.y;
    const int b = bh >> 3, h = bh & 7;
#pragma unroll
    for (int it = 0; it < 8; it++) {
        int chunk = tid + it * 256;
        int s = chunk >> 4, cc = chunk & 15;
        ushort8 v = *(const ushort8*)&QKV[(size_t)(b * S + st * 128 + s) * NQKV + 2048 + h * HD + cc * 8];
        *(ushort8*)&T[s * 136 + cc * 8] = v;
    }
    __syncthreads();
#pragma unroll
    for (int it = 0; it < 8; it++) {
        int chunk = tid + it * 256;
        int d = chunk >> 4, scc = chunk & 15;
        ushort8 o;
#pragma unroll
        for (int j = 0; j < 8; j++) o[j] = T[(scc * 8 + j) * 136 + d];
        *(ushort8*)&Vt[(size_t)((b * NKV + h) * HD + d) * S + st * 128 + scc * 8] = o;
    }
}

// ------------------------------------------- attention v3 (unchanged from R2)
// QBLK=64: grid (h, qt, b) = 8 x 32 x 2 = 512 blocks, 2 blocks/CU
__global__ __launch_bounds__(256, 2) void attn_kernel(const unsigned short* __restrict__ QKV,
                                                      const unsigned short* __restrict__ Vt,
                                                      unsigned short* __restrict__ Oout) {
    __shared__ unsigned short Ks[64 * 128];
    __shared__ unsigned short Vs[128 * 64];
    __shared__ unsigned short Ps[64 * 64];
    const int tid = threadIdx.x;
    const int lane = tid & 63, wave = tid >> 6;
    const int lm = lane & 15, quad = lane >> 4;
    const int sw = lm & 7;
    const int h = blockIdx.x;
    const int qt = blockIdx.y;
    const int b = blockIdx.z;
    const int qrow0 = qt * 64 + wave * 16;

    // Q fragments (A-layout: A[m=lm][k=quad*8+j]), scale already in wq_eff
    bf16x8 qf[4];
#pragma unroll
    for (int ks = 0; ks < 4; ks++) {
        size_t off = (size_t)(b * S + qrow0 + lm) * NQKV + h * HD + ks * 32 + quad * 8;
        qf[ks] = *(const bf16x8*)&QKV[off];
    }

    float lsum[4] = {};
    f32x4 oacc[8] = {};

    const int krow = tid >> 2, kc4 = tid & 3;
    const int vrow = tid >> 1, vc2 = tid & 1;
    const unsigned short* Kg0 = QKV + (size_t)(b * S) * NQKV + KV + h * HD + kc4 * 32;
    const unsigned short* Vg0 = Vt + (size_t)((b * NKV + h) * HD + vrow) * S + vc2 * 32;

    ushort8 kreg[4], vreg[4];
    {
        const unsigned short* kg = Kg0 + (size_t)krow * NQKV;
        const unsigned short* vg = Vg0;
#pragma unroll
        for (int j = 0; j < 4; j++) kreg[j] = *(const ushort8*)(kg + j * 8);
#pragma unroll
        for (int j = 0; j < 4; j++) vreg[j] = *(const ushort8*)(vg + j * 8);
    }

    for (int kt = 0; kt < 32; kt++) {
        __syncthreads();  // prior-iter LDS reads done; prefetch drained (needed now)
#pragma unroll
        for (int j = 0; j < 4; j++)
            *(ushort8*)&Ks[krow * 128 + ((kc4 * 4 + j) ^ (krow & 7)) * 8] = kreg[j];
#pragma unroll
        for (int j = 0; j < 4; j++)
            *(ushort8*)&Vs[vrow * 64 + ((vc2 * 4 + j) ^ (vrow & 7)) * 8] = vreg[j];
        __syncthreads();
        if (kt < 31) {  // prefetch next tile; overlaps all compute below
            const unsigned short* kg = Kg0 + (size_t)((kt + 1) * 64 + krow) * NQKV;
            const unsigned short* vg = Vg0 + (kt + 1) * 64;
#pragma unroll
            for (int j = 0; j < 4; j++) kreg[j] = *(const ushort8*)(kg + j * 8);
#pragma unroll
            for (int j = 0; j < 4; j++) vreg[j] = *(const ushort8*)(vg + j * 8);
        }

        // S = Q K^T : per wave 16q x 64k
        f32x4 sc[4] = {};
#pragma unroll
        for (int ks = 0; ks < 4; ks++)
#pragma unroll
            for (int ct = 0; ct < 4; ct++) {
                bf16x8 kf = *(const bf16x8*)&Ks[(ct * 16 + lm) * 128 + ((ks * 4 + quad) ^ sw) * 8];
                sc[ct] = __builtin_amdgcn_mfma_f32_16x16x32_bf16(qf[ks], kf, sc[ct], 0, 0, 0);
            }

        // p = exp(s); accumulate l from the bf16-rounded p (matches PV weights)
#pragma unroll
        for (int ct = 0; ct < 4; ct++)
#pragma unroll
            for (int r = 0; r < 4; r++) {
                float p = __expf(fminf(sc[ct][r], 60.f));
                unsigned short pb = f2bf(p);
                lsum[r] += bf2f(pb);
                int prow = wave * 16 + quad * 4 + r;
                int pcol = ct * 16 + lm;
                Ps[prow * 64 + (((pcol >> 3) ^ (prow & 7)) * 8) + (pcol & 7)] = pb;
            }

        // O += P V (own P rows only -> in-wave DS ordering, no barrier)
#pragma unroll
        for (int ks = 0; ks < 2; ks++) {
            bf16x8 af = *(const bf16x8*)&Ps[(wave * 16 + lm) * 64 + ((ks * 4 + quad) ^ sw) * 8];
#pragma unroll
            for (int dt = 0; dt < 8; dt++) {
                bf16x8 vf = *(const bf16x8*)&Vs[(dt * 16 + lm) * 64 + ((ks * 4 + quad) ^ sw) * 8];
                oacc[dt] = __builtin_amdgcn_mfma_f32_16x16x32_bf16(af, vf, oacc[dt], 0, 0, 0);
            }
        }
    }

    // final l reduction over the 16 lanes holding each row
#pragma unroll
    for (int r = 0; r < 4; r++) {
        float v = lsum[r];
        v += __shfl_xor(v, 8);
        v += __shfl_xor(v, 4);
        v += __shfl_xor(v, 2);
        v += __shfl_xor(v, 1);
        lsum[r] = v;
    }
#pragma unroll
    for (int dt = 0; dt < 8; dt++)
#pragma unroll
        for (int r = 0; r < 4; r++) {
            int row = b * S + qt * 64 + wave * 16 + quad * 4 + r;
            int col = h * HD + dt * 16 + lm;
            Oout[(size_t)row * KV + col] = f2bf(oacc[dt][r] / lsum[r]);
        }
}

// ----------------------------------------------------------------------------
extern "C" void kernel_launch(void* const* d_in, const int* in_sizes, int n_in,
                              void* d_out, int out_size, void* d_ws, size_t ws_size,
                              hipStream_t stream) {
    (void)in_sizes; (void)n_in; (void)out_size; (void)ws_size;
    const float* x  = (const float*)d_in[0];
    const float* wq = (const float*)d_in[1];
    const float* wk = (const float*)d_in[2];
    const float* wv = (const float*)d_in[3];
    const float* wo = (const float*)d_in[4];
    float* out = (float*)d_out;
    char* ws = (char*)d_ws;

    unsigned short* xb    = (unsigned short*)(ws);                         // 33.5MB
    unsigned short* WcatT = (unsigned short*)(ws + 33554432);              // 25.2MB
    unsigned short* woT   = (unsigned short*)(ws + 33554432 + 25165824);   // 8.4MB
    unsigned short* QKV   = (unsigned short*)(ws + 67108864);              // 25.2MB
    unsigned short* Vt    = (unsigned short*)(ws);                         // aliases dead xb
    unsigned short* AttnO = (unsigned short*)(ws + 8388608);               // aliases dead xb

    castx_kernel<<<16384, 256, 0, stream>>>(x, xb);
    wcat_kernel<<<dim3(64, 48), 256, 0, stream>>>(wq, wk, wv, WcatT);
    wot_kernel<<<dim3(16, 64), 256, 0, stream>>>(wo, woT);
    gemm_bt8<1><<<dim3(NQKV / 256, MROWS / 256), 512, 0, stream>>>(xb, WcatT, QKV, MROWS, NQKV, HID);
    vt_kernel<<<dim3(16, 16), 256, 0, stream>>>(QKV, Vt);
    attn_kernel<<<dim3(NKV, 32, BATCH), 256, 0, stream>>>(QKV, Vt, AttnO);
    gemm_bt8<0><<<dim3(HID / 256, MROWS / 256), 512, 0, stream>>>(AttnO, woT, out, MROWS, HID, KV);
}

// Round 4
// 416.561 us; speedup vs baseline: 1.0253x; 1.0253x over previous
//
#include <hip/hip_runtime.h>
#include <stdint.h>

#define S 2048
#define HID 4096
#define NKV 8
#define HD 128
#define KV 1024
#define BATCH 2
#define NQKV 3072   // KV*3 (q_eff | k | v)
#define MROWS 4096  // B*S

typedef __attribute__((ext_vector_type(4))) float f32x4;
typedef __attribute__((ext_vector_type(8))) __bf16 bf16x8;
typedef __attribute__((ext_vector_type(8))) unsigned short ushort8;
typedef __attribute__((ext_vector_type(4))) unsigned short ushort4_t;
typedef __attribute__((ext_vector_type(4))) float float4_t;

// fp32 -> bf16 bits, round-to-nearest-even
__device__ __forceinline__ unsigned short f2bf(float f) {
    unsigned int u = __builtin_bit_cast(unsigned int, f);
    u += 0x7fffu + ((u >> 16) & 1u);
    return (unsigned short)(u >> 16);
}
__device__ __forceinline__ float bf2f(unsigned short s) {
    unsigned int u = ((unsigned int)s) << 16;
    return __builtin_bit_cast(float, u);
}

// async global->LDS, 16B per lane. LDS dest must be wave-uniform base + lane*16.
__device__ __forceinline__ void gl2lds16(const void* g, void* l) {
    __builtin_amdgcn_global_load_lds(
        (const __attribute__((address_space(1))) void*)(uintptr_t)(g),
        (__attribute__((address_space(3))) void*)(uintptr_t)(l),
        16, 0, 0);
}

// ---------------------------------------------------------------- cast x->bf16
__global__ __launch_bounds__(256) void castx_kernel(const float* __restrict__ x,
                                                    unsigned short* __restrict__ xb) {
    int i = (blockIdx.x * 256 + threadIdx.x) * 4;
    float4_t v = *(const float4_t*)&x[i];
    ushort4_t o;
    o.x = f2bf(v.x); o.y = f2bf(v.y); o.z = f2bf(v.z); o.w = f2bf(v.w);
    *(ushort4_t*)&xb[i] = o;
}

// ------------------------------------------- build WcatT[3072][4096] bf16
__global__ __launch_bounds__(256) void wcat_kernel(const float* __restrict__ wq,
                                                   const float* __restrict__ wk,
                                                   const float* __restrict__ wv,
                                                   unsigned short* __restrict__ WcatT) {
    __shared__ float T[64 * 65];
    const int tid = threadIdx.x;
    const int k0 = blockIdx.x * 64;
    const int n0 = blockIdx.y * 64;
    const float scale = 0.088388347648318447f;  // 1/sqrt(128)
#pragma unroll
    for (int i = 0; i < 16; i++) {
        int kl = (tid >> 6) + i * 4;
        int nl = tid & 63;
        int k = k0 + kl, n = n0 + nl;
        float v;
        if (n < KV) {
            int kvh = n >> 7, d = n & 127;
            const float* p = wq + (size_t)k * HID + kvh * 512 + d;
            v = (p[0] + p[128] + p[256] + p[384]) * scale;
        } else if (n < 2048) {
            v = wk[(size_t)k * KV + (n - KV)];
        } else {
            v = wv[(size_t)k * KV + (n - 2048)];
        }
        T[kl * 65 + nl] = v;
    }
    __syncthreads();
#pragma unroll
    for (int i = 0; i < 16; i++) {
        int nl = (tid >> 6) + i * 4;
        int kl = tid & 63;
        WcatT[(size_t)(n0 + nl) * HID + k0 + kl] = f2bf(T[kl * 65 + nl]);
    }
}

// ------------------------------------------- build woT[4096][1024] bf16 (wo^T)
__global__ __launch_bounds__(256) void wot_kernel(const float* __restrict__ wo,
                                                  unsigned short* __restrict__ woT) {
    __shared__ float T[64 * 65];
    const int tid = threadIdx.x;
    const int k0 = blockIdx.x * 64;
    const int n0 = blockIdx.y * 64;
#pragma unroll
    for (int i = 0; i < 16; i++) {
        int kl = (tid >> 6) + i * 4, nl = tid & 63;
        T[kl * 65 + nl] = wo[(size_t)(k0 + kl) * HID + n0 + nl];
    }
    __syncthreads();
#pragma unroll
    for (int i = 0; i < 16; i++) {
        int nl = (tid >> 6) + i * 4, kl = tid & 63;
        woT[(size_t)(n0 + nl) * KV + k0 + kl] = f2bf(T[kl * 65 + nl]);
    }
}

// ============================================================================
// 256x256 8-phase GEMM: C[M][N] = A[M][K] * Bt[N][K]^T, bf16 in.
// 512 thr / 8 waves (2M x 4N); per-wave C = 128x64. BK=64, 2 K-tiles per iter.
// LDS: 2 dbuf x 2 row-halves x [128][64] for A and B = 128 KiB -> 1 block/CU.
// st_16x32 swizzle via inverse-permuted global SOURCE + XORed ds_read address.
// Bare s_barrier (NO memory-clobber asm) so lgkm waits stay per-wave/post-bar.
//
// R4: read-ahead register schedule at CONSTANT register cost (a[4][2] 32 +
// bn[2][2]+bh[2][2] 32 VGPR, same 64 as before). Same-phase-consumed read
// depth drops from 12 to <=4:
//   P1: rd A-lo.k1 + B-hi (8);       MFMA(0,0)[a,bn]   (a.k1 shallow-waited)
//   P2: MFMA(0,2)[a,bh]; rd A-hi (8 in MFMA shadow, same buf, resident)
//   P3: MFMA(4,2)[a,bh]              (operands ~1 phase old)
//   P4: MFMA(4,0)[a,bn]; vmcnt(6); rd NEXT-buf A-lo.k0 + B-lo (8, post-wait)
// Staging slots + vmcnt(6) retirement math unchanged from R2 (verified):
// at P4/P8 wait the 4 quarters of the tile consumed next are resident, 3
// stages stay in flight. WAR: every ds_read is lgkm-consumed by an MFMA >=2
// barriers before its LDS region restages; every stage lands >=1 barrier
// after the last read of the old data.
// ============================================================================
#define SBAR() __builtin_amdgcn_s_barrier()
#define SCHED0() __builtin_amdgcn_sched_barrier(0)
#define WAITV6() asm volatile("s_waitcnt vmcnt(6)")

// OUT_MODE: 0 = fp32 C, 1 = bf16 C, 2 = bf16 QKV with V-cols written to Vt
template <int OUT_MODE>
__global__ __launch_bounds__(512, 2) void gemm_bt8(const unsigned short* __restrict__ A,
                                                   const unsigned short* __restrict__ Bt,
                                                   void* __restrict__ Cv,
                                                   unsigned short* __restrict__ VtT,
                                                   int M, int N, int K) {
    __shared__ unsigned short As[2][2][8192];
    __shared__ unsigned short Bs[2][2][8192];
    const int tid = threadIdx.x;
    const int lane = tid & 63, wave = tid >> 6;
    const int lm = lane & 15, quad = lane >> 4;
    const int wm = wave >> 2;            // M-half of the block this wave owns
    const int wn = wave & 3;             // N quarter
    const int wnh = wn >> 1;             // B row-half
    const int wnb = (wn & 1) * 4;        // B subtile row-group base within half

    // ---- XCD-aware bijective block swizzle (nwg % 8 == 0 for both call sites)
    const int nbx = gridDim.x;
    const int id = blockIdx.y * nbx + blockIdx.x;
    const int cpx = (nbx * gridDim.y) >> 3;
    const int sid = (id & 7) * cpx + (id >> 3);
    const int m0 = (sid / nbx) * 256;
    const int n0 = (sid % nbx) * 256;

    // ---- staging source offsets (inverse-st_16x32-swizzled global chunks)
    size_t so0, so1;
    {
#pragma unroll
        for (int i = 0; i < 2; i++) {
            int p = i * 512 + tid;
            int ps = p ^ (((p >> 5) & 1) << 1);
            int s = ps >> 6, w = ps & 63;
            int row = ((s >> 1) << 4) + (w >> 2);
            int kc = ((s & 1) << 5) + ((w & 3) << 3);
            size_t off = (size_t)row * K + kc;
            if (i == 0) so0 = off; else so1 = off;
        }
    }
    const unsigned short* Agb = A + (size_t)m0 * K;
    const unsigned short* Bgb = Bt + (size_t)n0 * K;
    const size_t hK = (size_t)128 * K;

#define STLO(G, L) gl2lds16((G) + so0, (L) + (size_t)tid * 8)
#define STHI(G, L) gl2lds16((G) + so1, (L) + (size_t)(512 + tid) * 8)

    const int roff = lm * 32 + ((quad << 3) ^ (((lm >> 3) & 1) << 4));

#define RA(mi, kk, BUF) (*(const bf16x8*)&As[BUF][wm][(((mi) * 2 + (kk)) << 9) + roff])
#define RB(ni, kk, BUF) (*(const bf16x8*)&Bs[BUF][wnh][(((wnb + (ni)) * 2 + (kk)) << 9) + roff])
#define RD_A_LO_K0(BUF) { a[0][0]=RA(0,0,BUF); a[1][0]=RA(1,0,BUF); a[2][0]=RA(2,0,BUF); a[3][0]=RA(3,0,BUF); }
#define RD_A_LO_K1(BUF) { a[0][1]=RA(0,1,BUF); a[1][1]=RA(1,1,BUF); a[2][1]=RA(2,1,BUF); a[3][1]=RA(3,1,BUF); }
#define RD_A_HI(BUF)    { a[0][0]=RA(4,0,BUF); a[0][1]=RA(4,1,BUF); a[1][0]=RA(5,0,BUF); a[1][1]=RA(5,1,BUF); \
                          a[2][0]=RA(6,0,BUF); a[2][1]=RA(6,1,BUF); a[3][0]=RA(7,0,BUF); a[3][1]=RA(7,1,BUF); }
#define RD_BN(BUF) { bn[0][0]=RB(0,0,BUF); bn[0][1]=RB(0,1,BUF); bn[1][0]=RB(1,0,BUF); bn[1][1]=RB(1,1,BUF); }
#define RD_BH(BUF) { bh[0][0]=RB(2,0,BUF); bh[0][1]=RB(2,1,BUF); bh[1][0]=RB(3,0,BUF); bh[1][1]=RB(3,1,BUF); }
#define MFMA_Q(MB, NB, BB) do { \
    __builtin_amdgcn_s_setprio(1); \
    _Pragma("unroll") for (int i_ = 0; i_ < 4; i_++) \
    _Pragma("unroll") for (int j_ = 0; j_ < 2; j_++) \
    _Pragma("unroll") for (int k_ = 0; k_ < 2; k_++) \
        acc[(MB) + i_][(NB) + j_] = __builtin_amdgcn_mfma_f32_16x16x32_bf16( \
            a[i_][k_], BB[j_][k_], acc[(MB) + i_][(NB) + j_], 0, 0, 0); \
    __builtin_amdgcn_s_setprio(0); \
} while (0)

    f32x4 acc[8][4] = {};
    bf16x8 a[4][2], bn[2][2], bh[2][2];

    const int KT = K >> 6;   // 64-wide K-tiles
    const int NT = KT >> 1;  // iterations (2 tiles each)

    // ---- prologue: tile0 -> buf0 (8 quarters), tile1 -> buf1 (A-lo,B-lo,B-hi)
    STLO(Agb, &As[0][0][0]); STLO(Agb + hK, &As[0][1][0]);
    STHI(Agb, &As[0][0][0]); STHI(Agb + hK, &As[0][1][0]);
    STLO(Bgb, &Bs[0][0][0]); STLO(Bgb + hK, &Bs[0][1][0]);
    STHI(Bgb, &Bs[0][0][0]); STHI(Bgb + hK, &Bs[0][1][0]);
    STLO(Agb + 64, &As[1][0][0]); STLO(Agb + hK + 64, &As[1][1][0]);
    STLO(Bgb + 64, &Bs[1][0][0]); STLO(Bgb + hK + 64, &Bs[1][1][0]);
    STHI(Bgb + 64, &Bs[1][0][0]); STHI(Bgb + hK + 64, &Bs[1][1][0]);
    WAITV6();  // retire tile0's 8; tile1's 6 in flight
    SCHED0();
    RD_A_LO_K0(0); RD_BN(0);
    SBAR();

    for (int t = 0; t < NT; ++t) {
        const size_t k1 = (size_t)(2 * t + 1) * 64;
        int t2i = 2 * t + 2; if (t2i >= KT) t2i = KT - 1;  // tail: harmless restage
        int t3i = 2 * t + 3; if (t3i >= KT) t3i = KT - 1;
        const size_t k2 = (size_t)t2i * 64, k3 = (size_t)t3i * 64;

        // P1: rd buf0 A-lo.k1 + B-hi; stage buf1.A-hi <- t1
        RD_A_LO_K1(0); RD_BH(0);
        STHI(Agb + k1, &As[1][0][0]); STHI(Agb + hK + k1, &As[1][1][0]);
        SCHED0(); SBAR(); MFMA_Q(0, 0, bn); SBAR();

        // P2: stage buf0.A-lo <- t2; MFMA; rd buf0 A-hi in MFMA shadow
        STLO(Agb + k2, &As[0][0][0]); STLO(Agb + hK + k2, &As[0][1][0]);
        SCHED0(); SBAR(); MFMA_Q(0, 2, bh); RD_A_HI(0); SBAR();

        // P3: stage buf0.B-lo <- t2
        STLO(Bgb + k2, &Bs[0][0][0]); STLO(Bgb + hK + k2, &Bs[0][1][0]);
        SCHED0(); SBAR(); MFMA_Q(4, 2, bh); SBAR();

        // P4: stage buf0.B-hi <- t2; wait -> buf1/t1 resident; rd buf1 lead-ins
        STHI(Bgb + k2, &Bs[0][0][0]); STHI(Bgb + hK + k2, &Bs[0][1][0]);
        SCHED0(); SBAR(); MFMA_Q(4, 0, bn);
        WAITV6(); SCHED0();
        RD_A_LO_K0(1); RD_BN(1);
        SBAR();

        // P5: rd buf1 A-lo.k1 + B-hi; stage buf0.A-hi <- t2
        RD_A_LO_K1(1); RD_BH(1);
        STHI(Agb + k2, &As[0][0][0]); STHI(Agb + hK + k2, &As[0][1][0]);
        SCHED0(); SBAR(); MFMA_Q(0, 0, bn); SBAR();

        // P6: stage buf1.A-lo <- t3; MFMA; rd buf1 A-hi in shadow
        STLO(Agb + k3, &As[1][0][0]); STLO(Agb + hK + k3, &As[1][1][0]);
        SCHED0(); SBAR(); MFMA_Q(0, 2, bh); RD_A_HI(1); SBAR();

        // P7: stage buf1.B-lo <- t3
        STLO(Bgb + k3, &Bs[1][0][0]); STLO(Bgb + hK + k3, &Bs[1][1][0]);
        SCHED0(); SBAR(); MFMA_Q(4, 2, bh); SBAR();

        // P8: stage buf1.B-hi <- t3; wait -> buf0/t2 resident; rd buf0 lead-ins
        STHI(Bgb + k3, &Bs[1][0][0]); STHI(Bgb + hK + k3, &Bs[1][1][0]);
        SCHED0(); SBAR(); MFMA_Q(4, 0, bn);
        WAITV6(); SCHED0();
        RD_A_LO_K0(0); RD_BN(0);
        SBAR();
    }

    // ---- epilogue: C write (D layout: row = quad*4+r, col = lm)
    const int crow0 = m0 + wm * 128 + quad * 4;
    const int ccol0 = n0 + wn * 64 + lm;
    if (OUT_MODE == 2 && n0 >= 2048) {
        // V block: write transposed directly into Vt[(b*8+h)*128+d][s]
        const int bb = crow0 >> 11;          // wave-uniform (blocks don't straddle)
        const int s0 = crow0 & 2047;
        const int dbase = (n0 - 2048) + wn * 64;
#pragma unroll
        for (int mi = 0; mi < 8; mi++)
#pragma unroll
            for (int ni = 0; ni < 4; ni++) {
                int dcol = dbase + ni * 16 + lm;        // 0..1023
                int hh = dcol >> 7, dd = dcol & 127;    // h wave-uniform per (wn,ni)
                ushort4_t o;
#pragma unroll
                for (int r = 0; r < 4; r++) o[r] = f2bf(acc[mi][ni][r]);
                *(ushort4_t*)&VtT[(size_t)((bb * NKV + hh) * HD + dd) * S + s0 + mi * 16] = o;
            }
    } else {
#pragma unroll
        for (int mi = 0; mi < 8; mi++)
#pragma unroll
            for (int ni = 0; ni < 4; ni++)
#pragma unroll
                for (int r = 0; r < 4; r++) {
                    const int row = crow0 + mi * 16 + r;
                    const int col = ccol0 + ni * 16;
                    if (OUT_MODE == 0)
                        ((float*)Cv)[(size_t)row * N + col] = acc[mi][ni][r];
                    else
                        ((unsigned short*)Cv)[(size_t)row * N + col] = f2bf(acc[mi][ni][r]);
                }
    }
#undef RA
#undef RB
#undef RD_A_LO_K0
#undef RD_A_LO_K1
#undef RD_A_HI
#undef RD_BN
#undef RD_BH
#undef MFMA_Q
#undef STLO
#undef STHI
}

// ------------------------------------------- Vt[(b*8+h)*128 + d][s] from QKV v-part
// (fallback only, when workspace is too small for the fused Vt region)
__global__ __launch_bounds__(256) void vt_kernel(const unsigned short* __restrict__ QKV,
                                                 unsigned short* __restrict__ Vt) {
    __shared__ unsigned short T[128 * 136];
    const int tid = threadIdx.x;
    const int st = blockIdx.x;
    const int bh = blockIdx.y;
    const int b = bh >> 3, h = bh & 7;
#pragma unroll
    for (int it = 0; it < 8; it++) {
        int chunk = tid + it * 256;
        int s = chunk >> 4, cc = chunk & 15;
        ushort8 v = *(const ushort8*)&QKV[(size_t)(b * S + st * 128 + s) * NQKV + 2048 + h * HD + cc * 8];
        *(ushort8*)&T[s * 136 + cc * 8] = v;
    }
    __syncthreads();
#pragma unroll
    for (int it = 0; it < 8; it++) {
        int chunk = tid + it * 256;
        int d = chunk >> 4, scc = chunk & 15;
        ushort8 o;
#pragma unroll
        for (int j = 0; j < 8; j++) o[j] = T[(scc * 8 + j) * 136 + d];
        *(ushort8*)&Vt[(size_t)((b * NKV + h) * HD + d) * S + st * 128 + scc * 8] = o;
    }
}

// ------------------------------------------- attention v3 (unchanged)
// QBLK=64: grid (h, qt, b) = 8 x 32 x 2 = 512 blocks, 2 blocks/CU
__global__ __launch_bounds__(256, 2) void attn_kernel(const unsigned short* __restrict__ QKV,
                                                      const unsigned short* __restrict__ Vt,
                                                      unsigned short* __restrict__ Oout) {
    __shared__ unsigned short Ks[64 * 128];
    __shared__ unsigned short Vs[128 * 64];
    __shared__ unsigned short Ps[64 * 64];
    const int tid = threadIdx.x;
    const int lane = tid & 63, wave = tid >> 6;
    const int lm = lane & 15, quad = lane >> 4;
    const int sw = lm & 7;
    const int h = blockIdx.x;
    const int qt = blockIdx.y;
    const int b = blockIdx.z;
    const int qrow0 = qt * 64 + wave * 16;

    bf16x8 qf[4];
#pragma unroll
    for (int ks = 0; ks < 4; ks++) {
        size_t off = (size_t)(b * S + qrow0 + lm) * NQKV + h * HD + ks * 32 + quad * 8;
        qf[ks] = *(const bf16x8*)&QKV[off];
    }

    float lsum[4] = {};
    f32x4 oacc[8] = {};

    const int krow = tid >> 2, kc4 = tid & 3;
    const int vrow = tid >> 1, vc2 = tid & 1;
    const unsigned short* Kg0 = QKV + (size_t)(b * S) * NQKV + KV + h * HD + kc4 * 32;
    const unsigned short* Vg0 = Vt + (size_t)((b * NKV + h) * HD + vrow) * S + vc2 * 32;

    ushort8 kreg[4], vreg[4];
    {
        const unsigned short* kg = Kg0 + (size_t)krow * NQKV;
        const unsigned short* vg = Vg0;
#pragma unroll
        for (int j = 0; j < 4; j++) kreg[j] = *(const ushort8*)(kg + j * 8);
#pragma unroll
        for (int j = 0; j < 4; j++) vreg[j] = *(const ushort8*)(vg + j * 8);
    }

    for (int kt = 0; kt < 32; kt++) {
        __syncthreads();
#pragma unroll
        for (int j = 0; j < 4; j++)
            *(ushort8*)&Ks[krow * 128 + ((kc4 * 4 + j) ^ (krow & 7)) * 8] = kreg[j];
#pragma unroll
        for (int j = 0; j < 4; j++)
            *(ushort8*)&Vs[vrow * 64 + ((vc2 * 4 + j) ^ (vrow & 7)) * 8] = vreg[j];
        __syncthreads();
        if (kt < 31) {
            const unsigned short* kg = Kg0 + (size_t)((kt + 1) * 64 + krow) * NQKV;
            const unsigned short* vg = Vg0 + (kt + 1) * 64;
#pragma unroll
            for (int j = 0; j < 4; j++) kreg[j] = *(const ushort8*)(kg + j * 8);
#pragma unroll
            for (int j = 0; j < 4; j++) vreg[j] = *(const ushort8*)(vg + j * 8);
        }

        f32x4 sc[4] = {};
#pragma unroll
        for (int ks = 0; ks < 4; ks++)
#pragma unroll
            for (int ct = 0; ct < 4; ct++) {
                bf16x8 kf = *(const bf16x8*)&Ks[(ct * 16 + lm) * 128 + ((ks * 4 + quad) ^ sw) * 8];
                sc[ct] = __builtin_amdgcn_mfma_f32_16x16x32_bf16(qf[ks], kf, sc[ct], 0, 0, 0);
            }

#pragma unroll
        for (int ct = 0; ct < 4; ct++)
#pragma unroll
            for (int r = 0; r < 4; r++) {
                float p = __expf(fminf(sc[ct][r], 60.f));
                unsigned short pb = f2bf(p);
                lsum[r] += bf2f(pb);
                int prow = wave * 16 + quad * 4 + r;
                int pcol = ct * 16 + lm;
                Ps[prow * 64 + (((pcol >> 3) ^ (prow & 7)) * 8) + (pcol & 7)] = pb;
            }

#pragma unroll
        for (int ks = 0; ks < 2; ks++) {
            bf16x8 af = *(const bf16x8*)&Ps[(wave * 16 + lm) * 64 + ((ks * 4 + quad) ^ sw) * 8];
#pragma unroll
            for (int dt = 0; dt < 8; dt++) {
                bf16x8 vf = *(const bf16x8*)&Vs[(dt * 16 + lm) * 64 + ((ks * 4 + quad) ^ sw) * 8];
                oacc[dt] = __builtin_amdgcn_mfma_f32_16x16x32_bf16(af, vf, oacc[dt], 0, 0, 0);
            }
        }
    }

#pragma unroll
    for (int r = 0; r < 4; r++) {
        float v = lsum[r];
        v += __shfl_xor(v, 8);
        v += __shfl_xor(v, 4);
        v += __shfl_xor(v, 2);
        v += __shfl_xor(v, 1);
        lsum[r] = v;
    }
#pragma unroll
    for (int dt = 0; dt < 8; dt++)
#pragma unroll
        for (int r = 0; r < 4; r++) {
            int row = b * S + qt * 64 + wave * 16 + quad * 4 + r;
            int col = h * HD + dt * 16 + lm;
            Oout[(size_t)row * KV + col] = f2bf(oacc[dt][r] / lsum[r]);
        }
}

// ----------------------------------------------------------------------------
extern "C" void kernel_launch(void* const* d_in, const int* in_sizes, int n_in,
                              void* d_out, int out_size, void* d_ws, size_t ws_size,
                              hipStream_t stream) {
    (void)in_sizes; (void)n_in; (void)out_size;
    const float* x  = (const float*)d_in[0];
    const float* wq = (const float*)d_in[1];
    const float* wk = (const float*)d_in[2];
    const float* wv = (const float*)d_in[3];
    const float* wo = (const float*)d_in[4];
    float* out = (float*)d_out;
    char* ws = (char*)d_ws;

    unsigned short* xb    = (unsigned short*)(ws);                         // 33.5MB
    unsigned short* WcatT = (unsigned short*)(ws + 33554432);              // 25.2MB
    unsigned short* woT   = (unsigned short*)(ws + 33554432 + 25165824);   // 8.4MB
    unsigned short* QKV   = (unsigned short*)(ws + 67108864);              // 25.2MB
    unsigned short* AttnO = (unsigned short*)(ws + 8388608);               // aliases dead xb

    // Vt (8.4MB): fused path needs it disjoint from live xb/WcatT/QKV during
    // the QKV GEMM -> place after QKV if the workspace allows; else fall back
    // to the separate vt_kernel with Vt aliasing dead xb (old layout).
    const size_t VT_OFF = 67108864ull + 25165824ull;            // 92.3MB
    const int fuse_vt = (ws_size >= VT_OFF + 8388608ull);
    unsigned short* Vt = fuse_vt ? (unsigned short*)(ws + VT_OFF)
                                 : (unsigned short*)(ws);

    castx_kernel<<<16384, 256, 0, stream>>>(x, xb);
    wcat_kernel<<<dim3(64, 48), 256, 0, stream>>>(wq, wk, wv, WcatT);
    wot_kernel<<<dim3(16, 64), 256, 0, stream>>>(wo, woT);
    if (fuse_vt) {
        gemm_bt8<2><<<dim3(NQKV / 256, MROWS / 256), 512, 0, stream>>>(xb, WcatT, QKV, Vt, MROWS, NQKV, HID);
    } else {
        gemm_bt8<1><<<dim3(NQKV / 256, MROWS / 256), 512, 0, stream>>>(xb, WcatT, QKV, nullptr, MROWS, NQKV, HID);
        vt_kernel<<<dim3(16, 16), 256, 0, stream>>>(QKV, Vt);
    }
    attn_kernel<<<dim3(NKV, 32, BATCH), 256, 0, stream>>>(QKV, Vt, AttnO);
    gemm_bt8<0><<<dim3(HID / 256, MROWS / 256), 512, 0, stream>>>(AttnO, woT, out, nullptr, MROWS, HID, KV);
}

// Round 6
// 413.387 us; speedup vs baseline: 1.0332x; 1.0077x over previous
//
#include <hip/hip_runtime.h>
#include <stdint.h>

#define S 2048
#define HID 4096
#define NKV 8
#define HD 128
#define KV 1024
#define BATCH 2
#define NQKV 3072   // KV*3 (q_eff | k | v)
#define MROWS 4096  // B*S

typedef __attribute__((ext_vector_type(4))) float f32x4;
typedef __attribute__((ext_vector_type(8))) __bf16 bf16x8;
typedef __attribute__((ext_vector_type(8))) unsigned short ushort8;
typedef __attribute__((ext_vector_type(4))) unsigned short ushort4_t;
typedef __attribute__((ext_vector_type(4))) float float4_t;

// fp32 -> bf16 bits, round-to-nearest-even
__device__ __forceinline__ unsigned short f2bf(float f) {
    unsigned int u = __builtin_bit_cast(unsigned int, f);
    u += 0x7fffu + ((u >> 16) & 1u);
    return (unsigned short)(u >> 16);
}
__device__ __forceinline__ float bf2f(unsigned short s) {
    unsigned int u = ((unsigned int)s) << 16;
    return __builtin_bit_cast(float, u);
}

// async global->LDS, 16B per lane. LDS dest must be wave-uniform base + lane*16.
__device__ __forceinline__ void gl2lds16(const void* g, void* l) {
    __builtin_amdgcn_global_load_lds(
        (const __attribute__((address_space(1))) void*)(uintptr_t)(g),
        (__attribute__((address_space(3))) void*)(uintptr_t)(l),
        16, 0, 0);
}

// ============================================================================
// prep_kernel: castx + wcat + wot fused into one launch (saves 2 x ~10us
// launch/graph overhead; bodies are verbatim from the three validated
// kernels, dispatched by block-uniform blockIdx range -> no divergence,
// __syncthreads stays inside uniform branches).
//   blocks [0, 16384)          : castx  (x -> xb bf16)
//   blocks [16384, 19456)      : wcat   (WcatT[3072][4096], bb = 64x48)
//   blocks [19456, 20480)      : wot    (woT[4096][1024],  bb = 16x64)
// ============================================================================
__global__ __launch_bounds__(256) void prep_kernel(const float* __restrict__ x,
                                                   const float* __restrict__ wq,
                                                   const float* __restrict__ wk,
                                                   const float* __restrict__ wv,
                                                   const float* __restrict__ wo,
                                                   unsigned short* __restrict__ xb,
                                                   unsigned short* __restrict__ WcatT,
                                                   unsigned short* __restrict__ woT) {
    __shared__ float T[64 * 65];
    const int tid = threadIdx.x;
    const int blk = blockIdx.x;

    if (blk < 16384) {
        // ---- castx
        int i = (blk * 256 + tid) * 4;
        float4_t v = *(const float4_t*)&x[i];
        ushort4_t o;
        o.x = f2bf(v.x); o.y = f2bf(v.y); o.z = f2bf(v.z); o.w = f2bf(v.w);
        *(ushort4_t*)&xb[i] = o;
        return;
    }

    if (blk < 16384 + 3072) {
        // ---- wcat: build WcatT[3072][4096] bf16
        const int bb = blk - 16384;
        const int k0 = (bb & 63) * 64;
        const int n0 = (bb >> 6) * 64;
        const float scale = 0.088388347648318447f;  // 1/sqrt(128)
#pragma unroll
        for (int i = 0; i < 16; i++) {
            int kl = (tid >> 6) + i * 4;
            int nl = tid & 63;
            int k = k0 + kl, n = n0 + nl;
            float v;
            if (n < KV) {
                int kvh = n >> 7, d = n & 127;
                const float* p = wq + (size_t)k * HID + kvh * 512 + d;
                v = (p[0] + p[128] + p[256] + p[384]) * scale;
            } else if (n < 2048) {
                v = wk[(size_t)k * KV + (n - KV)];
            } else {
                v = wv[(size_t)k * KV + (n - 2048)];
            }
            T[kl * 65 + nl] = v;
        }
        __syncthreads();
#pragma unroll
        for (int i = 0; i < 16; i++) {
            int nl = (tid >> 6) + i * 4;
            int kl = tid & 63;
            WcatT[(size_t)(n0 + nl) * HID + k0 + kl] = f2bf(T[kl * 65 + nl]);
        }
        return;
    }

    // ---- wot: build woT[4096][1024] bf16 (wo^T)
    {
        const int bb = blk - 19456;
        const int k0 = (bb & 15) * 64;
        const int n0 = (bb >> 4) * 64;
#pragma unroll
        for (int i = 0; i < 16; i++) {
            int kl = (tid >> 6) + i * 4, nl = tid & 63;
            T[kl * 65 + nl] = wo[(size_t)(k0 + kl) * HID + n0 + nl];
        }
        __syncthreads();
#pragma unroll
        for (int i = 0; i < 16; i++) {
            int nl = (tid >> 6) + i * 4, kl = tid & 63;
            woT[(size_t)(n0 + nl) * KV + k0 + kl] = f2bf(T[kl * 65 + nl]);
        }
    }
}

// ============================================================================
// 256x256 8-phase GEMM: C[M][N] = A[M][K] * Bt[N][K]^T, bf16 in.
// (validated R3/R4 schedule — bare s_barrier, sched_barrier(0) fences,
//  read-ahead register schedule, quarter staging with vmcnt(6).)
// OUT_MODE: 0 = fp32 C, 1 = bf16 C, 2 = bf16 QKV with V-cols written to Vt
// ============================================================================
#define SBAR() __builtin_amdgcn_s_barrier()
#define SCHED0() __builtin_amdgcn_sched_barrier(0)
#define WAITV6() asm volatile("s_waitcnt vmcnt(6)")

template <int OUT_MODE>
__global__ __launch_bounds__(512, 2) void gemm_bt8(const unsigned short* __restrict__ A,
                                                   const unsigned short* __restrict__ Bt,
                                                   void* __restrict__ Cv,
                                                   unsigned short* __restrict__ VtT,
                                                   int M, int N, int K) {
    __shared__ unsigned short As[2][2][8192];
    __shared__ unsigned short Bs[2][2][8192];
    const int tid = threadIdx.x;
    const int lane = tid & 63, wave = tid >> 6;
    const int lm = lane & 15, quad = lane >> 4;
    const int wm = wave >> 2;            // M-half of the block this wave owns
    const int wn = wave & 3;             // N quarter
    const int wnh = wn >> 1;             // B row-half
    const int wnb = (wn & 1) * 4;        // B subtile row-group base within half

    // ---- XCD-aware bijective block swizzle (nwg % 8 == 0 for both call sites)
    const int nbx = gridDim.x;
    const int id = blockIdx.y * nbx + blockIdx.x;
    const int cpx = (nbx * gridDim.y) >> 3;
    const int sid = (id & 7) * cpx + (id >> 3);
    const int m0 = (sid / nbx) * 256;
    const int n0 = (sid % nbx) * 256;

    // ---- staging source offsets (inverse-st_16x32-swizzled global chunks)
    size_t so0, so1;
    {
#pragma unroll
        for (int i = 0; i < 2; i++) {
            int p = i * 512 + tid;
            int ps = p ^ (((p >> 5) & 1) << 1);
            int s = ps >> 6, w = ps & 63;
            int row = ((s >> 1) << 4) + (w >> 2);
            int kc = ((s & 1) << 5) + ((w & 3) << 3);
            size_t off = (size_t)row * K + kc;
            if (i == 0) so0 = off; else so1 = off;
        }
    }
    const unsigned short* Agb = A + (size_t)m0 * K;
    const unsigned short* Bgb = Bt + (size_t)n0 * K;
    const size_t hK = (size_t)128 * K;

#define STLO(G, L) gl2lds16((G) + so0, (L) + (size_t)tid * 8)
#define STHI(G, L) gl2lds16((G) + so1, (L) + (size_t)(512 + tid) * 8)

    const int roff = lm * 32 + ((quad << 3) ^ (((lm >> 3) & 1) << 4));

#define RA(mi, kk, BUF) (*(const bf16x8*)&As[BUF][wm][(((mi) * 2 + (kk)) << 9) + roff])
#define RB(ni, kk, BUF) (*(const bf16x8*)&Bs[BUF][wnh][(((wnb + (ni)) * 2 + (kk)) << 9) + roff])
#define RD_A_LO_K0(BUF) { a[0][0]=RA(0,0,BUF); a[1][0]=RA(1,0,BUF); a[2][0]=RA(2,0,BUF); a[3][0]=RA(3,0,BUF); }
#define RD_A_LO_K1(BUF) { a[0][1]=RA(0,1,BUF); a[1][1]=RA(1,1,BUF); a[2][1]=RA(2,1,BUF); a[3][1]=RA(3,1,BUF); }
#define RD_A_HI(BUF)    { a[0][0]=RA(4,0,BUF); a[0][1]=RA(4,1,BUF); a[1][0]=RA(5,0,BUF); a[1][1]=RA(5,1,BUF); \
                          a[2][0]=RA(6,0,BUF); a[2][1]=RA(6,1,BUF); a[3][0]=RA(7,0,BUF); a[3][1]=RA(7,1,BUF); }
#define RD_BN(BUF) { bn[0][0]=RB(0,0,BUF); bn[0][1]=RB(0,1,BUF); bn[1][0]=RB(1,0,BUF); bn[1][1]=RB(1,1,BUF); }
#define RD_BH(BUF) { bh[0][0]=RB(2,0,BUF); bh[0][1]=RB(2,1,BUF); bh[1][0]=RB(3,0,BUF); bh[1][1]=RB(3,1,BUF); }
#define MFMA_Q(MB, NB, BB) do { \
    __builtin_amdgcn_s_setprio(1); \
    _Pragma("unroll") for (int i_ = 0; i_ < 4; i_++) \
    _Pragma("unroll") for (int j_ = 0; j_ < 2; j_++) \
    _Pragma("unroll") for (int k_ = 0; k_ < 2; k_++) \
        acc[(MB) + i_][(NB) + j_] = __builtin_amdgcn_mfma_f32_16x16x32_bf16( \
            a[i_][k_], BB[j_][k_], acc[(MB) + i_][(NB) + j_], 0, 0, 0); \
    __builtin_amdgcn_s_setprio(0); \
} while (0)

    f32x4 acc[8][4] = {};
    bf16x8 a[4][2], bn[2][2], bh[2][2];

    const int KT = K >> 6;   // 64-wide K-tiles
    const int NT = KT >> 1;  // iterations (2 tiles each)

    // ---- prologue: tile0 -> buf0 (8 quarters), tile1 -> buf1 (A-lo,B-lo,B-hi)
    STLO(Agb, &As[0][0][0]); STLO(Agb + hK, &As[0][1][0]);
    STHI(Agb, &As[0][0][0]); STHI(Agb + hK, &As[0][1][0]);
    STLO(Bgb, &Bs[0][0][0]); STLO(Bgb + hK, &Bs[0][1][0]);
    STHI(Bgb, &Bs[0][0][0]); STHI(Bgb + hK, &Bs[0][1][0]);
    STLO(Agb + 64, &As[1][0][0]); STLO(Agb + hK + 64, &As[1][1][0]);
    STLO(Bgb + 64, &Bs[1][0][0]); STLO(Bgb + hK + 64, &Bs[1][1][0]);
    STHI(Bgb + 64, &Bs[1][0][0]); STHI(Bgb + hK + 64, &Bs[1][1][0]);
    WAITV6();  // retire tile0's 8; tile1's 6 in flight
    SCHED0();
    RD_A_LO_K0(0); RD_BN(0);
    SBAR();

    for (int t = 0; t < NT; ++t) {
        const size_t k1 = (size_t)(2 * t + 1) * 64;
        int t2i = 2 * t + 2; if (t2i >= KT) t2i = KT - 1;  // tail: harmless restage
        int t3i = 2 * t + 3; if (t3i >= KT) t3i = KT - 1;
        const size_t k2 = (size_t)t2i * 64, k3 = (size_t)t3i * 64;

        // P1: rd buf0 A-lo.k1 + B-hi; stage buf1.A-hi <- t1
        RD_A_LO_K1(0); RD_BH(0);
        STHI(Agb + k1, &As[1][0][0]); STHI(Agb + hK + k1, &As[1][1][0]);
        SCHED0(); SBAR(); MFMA_Q(0, 0, bn); SBAR();

        // P2: stage buf0.A-lo <- t2; MFMA; rd buf0 A-hi in MFMA shadow
        STLO(Agb + k2, &As[0][0][0]); STLO(Agb + hK + k2, &As[0][1][0]);
        SCHED0(); SBAR(); MFMA_Q(0, 2, bh); RD_A_HI(0); SBAR();

        // P3: stage buf0.B-lo <- t2
        STLO(Bgb + k2, &Bs[0][0][0]); STLO(Bgb + hK + k2, &Bs[0][1][0]);
        SCHED0(); SBAR(); MFMA_Q(4, 2, bh); SBAR();

        // P4: stage buf0.B-hi <- t2; wait -> buf1/t1 resident; rd buf1 lead-ins
        STHI(Bgb + k2, &Bs[0][0][0]); STHI(Bgb + hK + k2, &Bs[0][1][0]);
        SCHED0(); SBAR(); MFMA_Q(4, 0, bn);
        WAITV6(); SCHED0();
        RD_A_LO_K0(1); RD_BN(1);
        SBAR();

        // P5: rd buf1 A-lo.k1 + B-hi; stage buf0.A-hi <- t2
        RD_A_LO_K1(1); RD_BH(1);
        STHI(Agb + k2, &As[0][0][0]); STHI(Agb + hK + k2, &As[0][1][0]);
        SCHED0(); SBAR(); MFMA_Q(0, 0, bn); SBAR();

        // P6: stage buf1.A-lo <- t3; MFMA; rd buf1 A-hi in shadow
        STLO(Agb + k3, &As[1][0][0]); STLO(Agb + hK + k3, &As[1][1][0]);
        SCHED0(); SBAR(); MFMA_Q(0, 2, bh); RD_A_HI(1); SBAR();

        // P7: stage buf1.B-lo <- t3
        STLO(Bgb + k3, &Bs[1][0][0]); STLO(Bgb + hK + k3, &Bs[1][1][0]);
        SCHED0(); SBAR(); MFMA_Q(4, 2, bh); SBAR();

        // P8: stage buf1.B-hi <- t3; wait -> buf0/t2 resident; rd buf0 lead-ins
        STHI(Bgb + k3, &Bs[1][0][0]); STHI(Bgb + hK + k3, &Bs[1][1][0]);
        SCHED0(); SBAR(); MFMA_Q(4, 0, bn);
        WAITV6(); SCHED0();
        RD_A_LO_K0(0); RD_BN(0);
        SBAR();
    }

    // ---- epilogue: C write (D layout: row = quad*4+r, col = lm)
    const int crow0 = m0 + wm * 128 + quad * 4;
    const int ccol0 = n0 + wn * 64 + lm;
    if (OUT_MODE == 2 && n0 >= 2048) {
        // V block: write transposed directly into Vt[(b*8+h)*128+d][s]
        const int bb = crow0 >> 11;          // wave-uniform (blocks don't straddle)
        const int s0 = crow0 & 2047;
        const int dbase = (n0 - 2048) + wn * 64;
#pragma unroll
        for (int mi = 0; mi < 8; mi++)
#pragma unroll
            for (int ni = 0; ni < 4; ni++) {
                int dcol = dbase + ni * 16 + lm;        // 0..1023
                int hh = dcol >> 7, dd = dcol & 127;
                ushort4_t o;
#pragma unroll
                for (int r = 0; r < 4; r++) o[r] = f2bf(acc[mi][ni][r]);
                *(ushort4_t*)&VtT[(size_t)((bb * NKV + hh) * HD + dd) * S + s0 + mi * 16] = o;
            }
    } else {
#pragma unroll
        for (int mi = 0; mi < 8; mi++)
#pragma unroll
            for (int ni = 0; ni < 4; ni++)
#pragma unroll
                for (int r = 0; r < 4; r++) {
                    const int row = crow0 + mi * 16 + r;
                    const int col = ccol0 + ni * 16;
                    if (OUT_MODE == 0)
                        ((float*)Cv)[(size_t)row * N + col] = acc[mi][ni][r];
                    else
                        ((unsigned short*)Cv)[(size_t)row * N + col] = f2bf(acc[mi][ni][r]);
                }
    }
#undef RA
#undef RB
#undef RD_A_LO_K0
#undef RD_A_LO_K1
#undef RD_A_HI
#undef RD_BN
#undef RD_BH
#undef MFMA_Q
#undef STLO
#undef STHI
}

// ------------------------------------------- Vt[(b*8+h)*128 + d][s] from QKV v-part
// (fallback only, when workspace is too small for the fused Vt region)
__global__ __launch_bounds__(256) void vt_kernel(const unsigned short* __restrict__ QKV,
                                                 unsigned short* __restrict__ Vt) {
    __shared__ unsigned short T[128 * 136];
    const int tid = threadIdx.x;
    const int st = blockIdx.x;
    const int bh = blockIdx.y;
    const int b = bh >> 3, h = bh & 7;
#pragma unroll
    for (int it = 0; it < 8; it++) {
        int chunk = tid + it * 256;
        int s = chunk >> 4, cc = chunk & 15;
        ushort8 v = *(const ushort8*)&QKV[(size_t)(b * S + st * 128 + s) * NQKV + 2048 + h * HD + cc * 8];
        *(ushort8*)&T[s * 136 + cc * 8] = v;
    }
    __syncthreads();
#pragma unroll
    for (int it = 0; it < 8; it++) {
        int chunk = tid + it * 256;
        int d = chunk >> 4, scc = chunk & 15;
        ushort8 o;
#pragma unroll
        for (int j = 0; j < 8; j++) o[j] = T[(scc * 8 + j) * 136 + d];
        *(ushort8*)&Vt[(size_t)((b * NKV + h) * HD + d) * S + st * 128 + scc * 8] = o;
    }
}

// ------------------------------------------- attention v3 (unchanged, validated)
// QBLK=64: grid (h, qt, b) = 8 x 32 x 2 = 512 blocks, 2 blocks/CU
__global__ __launch_bounds__(256, 2) void attn_kernel(const unsigned short* __restrict__ QKV,
                                                      const unsigned short* __restrict__ Vt,
                                                      unsigned short* __restrict__ Oout) {
    __shared__ unsigned short Ks[64 * 128];
    __shared__ unsigned short Vs[128 * 64];
    __shared__ unsigned short Ps[64 * 64];
    const int tid = threadIdx.x;
    const int lane = tid & 63, wave = tid >> 6;
    const int lm = lane & 15, quad = lane >> 4;
    const int sw = lm & 7;
    const int h = blockIdx.x;
    const int qt = blockIdx.y;
    const int b = blockIdx.z;
    const int qrow0 = qt * 64 + wave * 16;

    bf16x8 qf[4];
#pragma unroll
    for (int ks = 0; ks < 4; ks++) {
        size_t off = (size_t)(b * S + qrow0 + lm) * NQKV + h * HD + ks * 32 + quad * 8;
        qf[ks] = *(const bf16x8*)&QKV[off];
    }

    float lsum[4] = {};
    f32x4 oacc[8] = {};

    const int krow = tid >> 2, kc4 = tid & 3;
    const int vrow = tid >> 1, vc2 = tid & 1;
    const unsigned short* Kg0 = QKV + (size_t)(b * S) * NQKV + KV + h * HD + kc4 * 32;
    const unsigned short* Vg0 = Vt + (size_t)((b * NKV + h) * HD + vrow) * S + vc2 * 32;

    ushort8 kreg[4], vreg[4];
    {
        const unsigned short* kg = Kg0 + (size_t)krow * NQKV;
        const unsigned short* vg = Vg0;
#pragma unroll
        for (int j = 0; j < 4; j++) kreg[j] = *(const ushort8*)(kg + j * 8);
#pragma unroll
        for (int j = 0; j < 4; j++) vreg[j] = *(const ushort8*)(vg + j * 8);
    }

    for (int kt = 0; kt < 32; kt++) {
        __syncthreads();
#pragma unroll
        for (int j = 0; j < 4; j++)
            *(ushort8*)&Ks[krow * 128 + ((kc4 * 4 + j) ^ (krow & 7)) * 8] = kreg[j];
#pragma unroll
        for (int j = 0; j < 4; j++)
            *(ushort8*)&Vs[vrow * 64 + ((vc2 * 4 + j) ^ (vrow & 7)) * 8] = vreg[j];
        __syncthreads();
        if (kt < 31) {
            const unsigned short* kg = Kg0 + (size_t)((kt + 1) * 64 + krow) * NQKV;
            const unsigned short* vg = Vg0 + (kt + 1) * 64;
#pragma unroll
            for (int j = 0; j < 4; j++) kreg[j] = *(const ushort8*)(kg + j * 8);
#pragma unroll
            for (int j = 0; j < 4; j++) vreg[j] = *(const ushort8*)(vg + j * 8);
        }

        f32x4 sc[4] = {};
#pragma unroll
        for (int ks = 0; ks < 4; ks++)
#pragma unroll
            for (int ct = 0; ct < 4; ct++) {
                bf16x8 kf = *(const bf16x8*)&Ks[(ct * 16 + lm) * 128 + ((ks * 4 + quad) ^ sw) * 8];
                sc[ct] = __builtin_amdgcn_mfma_f32_16x16x32_bf16(qf[ks], kf, sc[ct], 0, 0, 0);
            }

#pragma unroll
        for (int ct = 0; ct < 4; ct++)
#pragma unroll
            for (int r = 0; r < 4; r++) {
                float p = __expf(fminf(sc[ct][r], 60.f));
                unsigned short pb = f2bf(p);
                lsum[r] += bf2f(pb);
                int prow = wave * 16 + quad * 4 + r;
                int pcol = ct * 16 + lm;
                Ps[prow * 64 + (((pcol >> 3) ^ (prow & 7)) * 8) + (pcol & 7)] = pb;
            }

#pragma unroll
        for (int ks = 0; ks < 2; ks++) {
            bf16x8 af = *(const bf16x8*)&Ps[(wave * 16 + lm) * 64 + ((ks * 4 + quad) ^ sw) * 8];
#pragma unroll
            for (int dt = 0; dt < 8; dt++) {
                bf16x8 vf = *(const bf16x8*)&Vs[(dt * 16 + lm) * 64 + ((ks * 4 + quad) ^ sw) * 8];
                oacc[dt] = __builtin_amdgcn_mfma_f32_16x16x32_bf16(af, vf, oacc[dt], 0, 0, 0);
            }
        }
    }

#pragma unroll
    for (int r = 0; r < 4; r++) {
        float v = lsum[r];
        v += __shfl_xor(v, 8);
        v += __shfl_xor(v, 4);
        v += __shfl_xor(v, 2);
        v += __shfl_xor(v, 1);
        lsum[r] = v;
    }
#pragma unroll
    for (int dt = 0; dt < 8; dt++)
#pragma unroll
        for (int r = 0; r < 4; r++) {
            int row = b * S + qt * 64 + wave * 16 + quad * 4 + r;
            int col = h * HD + dt * 16 + lm;
            Oout[(size_t)row * KV + col] = f2bf(oacc[dt][r] / lsum[r]);
        }
}

// ----------------------------------------------------------------------------
extern "C" void kernel_launch(void* const* d_in, const int* in_sizes, int n_in,
                              void* d_out, int out_size, void* d_ws, size_t ws_size,
                              hipStream_t stream) {
    (void)in_sizes; (void)n_in; (void)out_size;
    const float* x  = (const float*)d_in[0];
    const float* wq = (const float*)d_in[1];
    const float* wk = (const float*)d_in[2];
    const float* wv = (const float*)d_in[3];
    const float* wo = (const float*)d_in[4];
    float* out = (float*)d_out;
    char* ws = (char*)d_ws;

    unsigned short* xb    = (unsigned short*)(ws);                         // 33.5MB
    unsigned short* WcatT = (unsigned short*)(ws + 33554432);              // 25.2MB
    unsigned short* woT   = (unsigned short*)(ws + 33554432 + 25165824);   // 8.4MB
    unsigned short* QKV   = (unsigned short*)(ws + 67108864);              // 25.2MB
    unsigned short* AttnO = (unsigned short*)(ws + 8388608);               // aliases dead xb

    // Vt (8.4MB): fused path needs it disjoint from live xb/WcatT/QKV during
    // the QKV GEMM -> place after QKV if the workspace allows; else fall back
    // to the separate vt_kernel with Vt aliasing dead xb (old layout).
    const size_t VT_OFF = 67108864ull + 25165824ull;            // 92.3MB
    const int fuse_vt = (ws_size >= VT_OFF + 8388608ull);
    unsigned short* Vt = fuse_vt ? (unsigned short*)(ws + VT_OFF)
                                 : (unsigned short*)(ws);

    prep_kernel<<<20480, 256, 0, stream>>>(x, wq, wk, wv, wo, xb, WcatT, woT);
    if (fuse_vt) {
        gemm_bt8<2><<<dim3(NQKV / 256, MROWS / 256), 512, 0, stream>>>(xb, WcatT, QKV, Vt, MROWS, NQKV, HID);
    } else {
        gemm_bt8<1><<<dim3(NQKV / 256, MROWS / 256), 512, 0, stream>>>(xb, WcatT, QKV, nullptr, MROWS, NQKV, HID);
        vt_kernel<<<dim3(16, 16), 256, 0, stream>>>(QKV, Vt);
    }
    attn_kernel<<<dim3(NKV, 32, BATCH), 256, 0, stream>>>(QKV, Vt, AttnO);
    gemm_bt8<0><<<dim3(HID / 256, MROWS / 256), 512, 0, stream>>>(AttnO, woT, out, nullptr, MROWS, HID, KV);
}